// Round 3
// baseline (126.940 us; speedup 1.0000x reference)
//
#include <hip/hip_runtime.h>
#include <hip/hip_bf16.h>

#define NQ 8192
#define NK 8192
#define DH 128
#define KVBLK 32
#define SLICES 16
#define KVPER (NK / SLICES)          // 512 kv per slice
#define TILES (KVPER / KVBLK)        // 16 tiles per sweep
#define NTILES (NK / KVBLK)          // 256 global tiles

typedef __attribute__((ext_vector_type(8))) short short8;
typedef __attribute__((ext_vector_type(8))) unsigned short ushort8v;
typedef __attribute__((ext_vector_type(16))) float f32x16;

static __device__ __forceinline__ unsigned short f2bf(float x){
  unsigned u = __builtin_bit_cast(unsigned, x);
  u += 0x7FFFu + ((u >> 16) & 1u);
  return (unsigned short)(u >> 16);
}
static __device__ __forceinline__ float bf2f(unsigned short x){
  unsigned u = ((unsigned)x) << 16;
  return __builtin_bit_cast(float, u);
}
static __device__ __forceinline__ void gload_lds16(const void* g, void* l){
  __builtin_amdgcn_global_load_lds((const __attribute__((address_space(1))) void*)g,
                                   (__attribute__((address_space(3))) void*)l,
                                   16, 0, 0);
}

// ---- prep: Q fp32 -> bf16, scaled by log2(e)/sqrt(128) (log2-domain softmax) --
__global__ __launch_bounds__(512) void prep_q(const float4* __restrict__ Q4,
                                              ushort8v* __restrict__ Qb8)
{
  int i = blockIdx.x * 512 + threadIdx.x;
  const float s = 1.4426950408889634f * 0.08838834764831844f;
  float4 a = Q4[2 * i], b = Q4[2 * i + 1];
  ushort8v o;
  o[0]=f2bf(a.x*s); o[1]=f2bf(a.y*s); o[2]=f2bf(a.z*s); o[3]=f2bf(a.w*s);
  o[4]=f2bf(b.x*s); o[5]=f2bf(b.y*s); o[6]=f2bf(b.z*s); o[7]=f2bf(b.w*s);
  Qb8[i] = o;
}

// ---- prep: K,V fp32 -> tiled/permuted/XOR-swizzled bf16 images (8KB tiles) ---
// K tile: K[kv][d] at byte (kv*256 + d*2) ^ ((kv&7)<<4)
// V tile: row d (64B): slot j=mm*16+h*8+p*4+e holds kv=mm*16+p*8+h*4+e,
//         16B granule at byte d*64 + (mm*32+h*16)^((d&3)<<4)
__global__ __launch_bounds__(256) void prep_kv(const float* __restrict__ K,
                                               const float* __restrict__ V,
                                               unsigned char* __restrict__ Kt,
                                               unsigned char* __restrict__ Vt)
{
  __shared__ float vs[KVBLK * DH];             // 16 KiB
  const int tile = blockIdx.x;                 // 256 tiles
  const int tid  = threadIdx.x;

  const float4* Vg = (const float4*)(V + (size_t)tile * KVBLK * DH);
  float4* vs4 = (float4*)vs;
#pragma unroll
  for (int k = 0; k < 4; ++k) vs4[tid + k * 256] = Vg[tid + k * 256];

  unsigned char* Ktb = Kt + (size_t)tile * 8192;
  const float* Kg = K + (size_t)tile * KVBLK * DH;
#pragma unroll
  for (int k2 = 0; k2 < 2; ++k2){
    int task = tid + k2 * 256;                 // 512 tasks: (kv, d0)
    int kv = task >> 4, d0 = (task & 15) * 8;
    const float4* p = (const float4*)(Kg + kv * DH + d0);
    float4 a = p[0], b = p[1];
    ushort8v o;
    o[0]=f2bf(a.x); o[1]=f2bf(a.y); o[2]=f2bf(a.z); o[3]=f2bf(a.w);
    o[4]=f2bf(b.x); o[5]=f2bf(b.y); o[6]=f2bf(b.z); o[7]=f2bf(b.w);
    int addr = (kv * 256 + d0 * 2) ^ ((kv & 7) << 4);
    *(ushort8v*)(Ktb + addr) = o;
  }
  __syncthreads();

  unsigned char* Vtb = Vt + (size_t)tile * 8192;
#pragma unroll
  for (int k2 = 0; k2 < 2; ++k2){
    int task = tid + k2 * 256;                 // 512 tasks: (d, mm, h)
    int d = task >> 2, mm = (task >> 1) & 1, hh = task & 1;
    int kvb = mm * 16 + hh * 4;
    ushort8v o;
    o[0]=f2bf(vs[(kvb+0)*DH + d]);  o[1]=f2bf(vs[(kvb+1)*DH + d]);
    o[2]=f2bf(vs[(kvb+2)*DH + d]);  o[3]=f2bf(vs[(kvb+3)*DH + d]);
    o[4]=f2bf(vs[(kvb+8)*DH + d]);  o[5]=f2bf(vs[(kvb+9)*DH + d]);
    o[6]=f2bf(vs[(kvb+10)*DH + d]); o[7]=f2bf(vs[(kvb+11)*DH + d]);
    int addr = d * 64 + ((mm * 32 + hh * 16) ^ ((d & 3) << 4));
    *(ushort8v*)(Vtb + addr) = o;
  }
}

// ---- main: 4 waves x 64 q-rows, Q-reuse (1 LDS frag -> 2 MFMA), dbuf LDS -----
__global__ __launch_bounds__(256, 2) void attn_kernel(
    const unsigned short* __restrict__ Qb,
    const unsigned char* __restrict__ Kt,
    const unsigned char* __restrict__ Vt,
    unsigned short* __restrict__ Opart,   // [SLICES][NQ][DH] bf16
    float* __restrict__ Mpart, float* __restrict__ Lpart)
{
  __shared__ unsigned char lK[2][8192];
  __shared__ unsigned char lV[2][8192];

  const int tid  = threadIdx.x;
  const int lane = tid & 63;
  const int wave = tid >> 6;               // 0..3
  const int l32  = lane & 31;
  const int h    = lane >> 5;
  const int bq    = blockIdx.x >> 4;       // 0..31
  const int slice = blockIdx.x & 15;       // slice%8 == XCD (L2 locality)
  const int qrow0 = bq * 256 + wave * 64;
  const int tile0 = slice * TILES;
  const int kx = (l32 & 7) << 4;
  const int vx = (l32 & 3) << 4;

  const unsigned char* gkb = Kt + (size_t)tile0 * 8192;
  const unsigned char* gvb = Vt + (size_t)tile0 * 8192;

  // Q fragments for two 32-row blocks (A: rows +l32, B: rows +32+l32)
  short8 qfA[8], qfB[8];
  {
    const unsigned short* qa = Qb + (size_t)(qrow0 + l32) * DH + 8 * h;
    const unsigned short* qb = qa + 32 * DH;
#pragma unroll
    for (int m = 0; m < 8; ++m){
      qfA[m] = *(const short8*)(qa + 16 * m);
      qfB[m] = *(const short8*)(qb + 16 * m);
    }
  }

  f32x16 accA[4], accB[4];
#pragma unroll
  for (int c = 0; c < 4; ++c)
#pragma unroll
    for (int r = 0; r < 16; ++r){ accA[c][r] = 0.0f; accB[c][r] = 0.0f; }
  float mA = -3.0e38f, lA = 0.0f, mB = -3.0e38f, lB = 0.0f;

  const int soff = tid * 16;
  auto stage = [&](int buf, int t){
    const unsigned char* gk = gkb + (size_t)t * 8192;
    const unsigned char* gv = gvb + (size_t)t * 8192;
    gload_lds16(gk + soff,        &lK[buf][soff]);
    gload_lds16(gk + soff + 4096, &lK[buf][soff + 4096]);
    gload_lds16(gv + soff,        &lV[buf][soff]);
    gload_lds16(gv + soff + 4096, &lV[buf][soff + 4096]);
  };

  stage(0, 0);
  __syncthreads();
  int cur = 0;

  for (int t = 0; t < TILES; ++t){
    if (t + 1 < TILES) stage(cur ^ 1, t + 1);

    const unsigned char* Kb = lK[cur];
    const unsigned char* Vb = lV[cur];

    // ---- S^T = K * Q^T : each K-fragment feeds both q-blocks
    f32x16 SA, SB;
#pragma unroll
    for (int r = 0; r < 16; ++r){ SA[r] = 0.0f; SB[r] = 0.0f; }
    __builtin_amdgcn_s_setprio(1);
#pragma unroll
    for (int m = 0; m < 8; ++m){
      short8 kf = *(const short8*)(Kb + l32 * 256 + ((32 * m + 16 * h) ^ kx));
      SA = __builtin_amdgcn_mfma_f32_32x32x16_bf16(kf, qfA[m], SA, 0, 0, 0);
      SB = __builtin_amdgcn_mfma_f32_32x32x16_bf16(kf, qfB[m], SB, 0, 0, 0);
    }
    __builtin_amdgcn_s_setprio(0);

    // ---- online softmax (log2 domain), block A then B
    float pmA = -3.0e38f, pmB = -3.0e38f;
#pragma unroll
    for (int r = 0; r < 16; ++r){
      pmA = fmaxf(pmA, SA[r]);
      pmB = fmaxf(pmB, SB[r]);
    }
    pmA = fmaxf(pmA, __shfl_xor(pmA, 32, 64));
    pmB = fmaxf(pmB, __shfl_xor(pmB, 32, 64));

    if (!__all(pmA <= mA + 8.0f)){
      float mnew = fmaxf(mA, pmA);
      float rs = exp2f(mA - mnew);
      lA *= rs; mA = mnew;
#pragma unroll
      for (int r = 0; r < 16; ++r){
        float f = __shfl(rs, (r & 3) + 8 * (r >> 2) + 4 * h, 64);
#pragma unroll
        for (int c = 0; c < 4; ++c) accA[c][r] *= f;
      }
    }
    if (!__all(pmB <= mB + 8.0f)){
      float mnew = fmaxf(mB, pmB);
      float rs = exp2f(mB - mnew);
      lB *= rs; mB = mnew;
#pragma unroll
      for (int r = 0; r < 16; ++r){
        float f = __shfl(rs, (r & 3) + 8 * (r >> 2) + 4 * h, 64);
#pragma unroll
        for (int c = 0; c < 4; ++c) accB[c][r] *= f;
      }
    }

    float psA = 0.0f, psB = 0.0f;
#pragma unroll
    for (int r = 0; r < 16; ++r){
      SA[r] = exp2f(SA[r] - mA);
      SB[r] = exp2f(SB[r] - mB);
      psA += SA[r]; psB += SB[r];
    }
    psA += __shfl_xor(psA, 32, 64);
    psB += __shfl_xor(psB, 32, 64);
    lA += psA; lB += psB;

    short8 paA[2], paB[2];
#pragma unroll
    for (int e = 0; e < 8; ++e){
      paA[0][e] = (short)f2bf(SA[e]);
      paA[1][e] = (short)f2bf(SA[8 + e]);
      paB[0][e] = (short)f2bf(SB[e]);
      paB[1][e] = (short)f2bf(SB[8 + e]);
    }

    // ---- PV: each V-fragment feeds both q-blocks
    __builtin_amdgcn_s_setprio(1);
#pragma unroll
    for (int c = 0; c < 4; ++c){
      const unsigned char* vrow = Vb + (32 * c + l32) * 64;
      short8 v0 = *(const short8*)(vrow + ((16 * h) ^ vx));
      short8 v1 = *(const short8*)(vrow + ((32 + 16 * h) ^ vx));
      accA[c] = __builtin_amdgcn_mfma_f32_32x32x16_bf16(paA[0], v0, accA[c], 0, 0, 0);
      accB[c] = __builtin_amdgcn_mfma_f32_32x32x16_bf16(paB[0], v0, accB[c], 0, 0, 0);
      accA[c] = __builtin_amdgcn_mfma_f32_32x32x16_bf16(paA[1], v1, accA[c], 0, 0, 0);
      accB[c] = __builtin_amdgcn_mfma_f32_32x32x16_bf16(paB[1], v1, accB[c], 0, 0, 0);
    }
    __builtin_amdgcn_s_setprio(0);

    __syncthreads();
    cur ^= 1;
  }

  // ---- partials out (bf16 O, fp32 m/l, all log2-domain)
  if (h == 0){
    Mpart[slice * NQ + qrow0 + l32] = mA;
    Lpart[slice * NQ + qrow0 + l32] = lA;
    Mpart[slice * NQ + qrow0 + 32 + l32] = mB;
    Lpart[slice * NQ + qrow0 + 32 + l32] = lB;
  }
  const size_t obase = ((size_t)slice * NQ + qrow0) * DH;
#pragma unroll
  for (int c = 0; c < 4; ++c)
#pragma unroll
    for (int r = 0; r < 16; ++r){
      int q = (r & 3) + 8 * (r >> 2) + 4 * h;
      Opart[obase + (size_t)q * DH + 32 * c + l32]        = f2bf(accA[c][r]);
      Opart[obase + (size_t)(32 + q) * DH + 32 * c + l32] = f2bf(accB[c][r]);
    }
}

// ---- combine 16 kv-slice partials ------------------------------------------
__global__ __launch_bounds__(256) void combine_kernel(
    const unsigned short* __restrict__ Op, const float* __restrict__ Mp,
    const float* __restrict__ Lp, float* __restrict__ Out)
{
  const int idx = blockIdx.x * 256 + threadIdx.x;
  const int q  = idx >> 4;
  const int d8 = (idx & 15) * 8;

  float ms[SLICES], M = -3.0e38f;
#pragma unroll
  for (int s = 0; s < SLICES; ++s){ ms[s] = Mp[s * NQ + q]; M = fmaxf(M, ms[s]); }
  float w[SLICES], L = 0.0f;
#pragma unroll
  for (int s = 0; s < SLICES; ++s){
    w[s] = exp2f(ms[s] - M);
    L += Lp[s * NQ + q] * w[s];
  }
  float o[8] = {0,0,0,0,0,0,0,0};
#pragma unroll
  for (int s = 0; s < SLICES; ++s){
    ushort8v v = *(const ushort8v*)(Op + ((size_t)s * NQ + q) * DH + d8);
    float ww = w[s];
#pragma unroll
    for (int e = 0; e < 8; ++e) o[e] += ww * bf2f(v[e]);
  }
  float inv = 1.0f / L;
  float4 o0 = make_float4(o[0]*inv, o[1]*inv, o[2]*inv, o[3]*inv);
  float4 o1 = make_float4(o[4]*inv, o[5]*inv, o[6]*inv, o[7]*inv);
  float4* dst = (float4*)(Out + (size_t)q * DH + d8);
  dst[0] = o0; dst[1] = o1;
}

extern "C" void kernel_launch(void* const* d_in, const int* in_sizes, int n_in,
                              void* d_out, int out_size, void* d_ws, size_t ws_size,
                              hipStream_t stream)
{
  const float* Q = (const float*)d_in[0];
  const float* K = (const float*)d_in[1];
  const float* V = (const float*)d_in[2];

  unsigned char* ws = (unsigned char*)d_ws;
  const size_t MB2 = (size_t)NQ * DH * 2;            // 2 MiB
  unsigned short* Qb = (unsigned short*)ws;          // 2 MiB
  unsigned char*  Kt = ws + MB2;                     // 2 MiB
  unsigned char*  Vt = ws + 2 * MB2;                 // 2 MiB
  float* Mp = (float*)(ws + 3 * MB2);                // 512 KiB
  float* Lp = Mp + (size_t)SLICES * NQ;              // 512 KiB
  unsigned short* Op = (unsigned short*)(Lp + (size_t)SLICES * NQ);  // 32 MiB

  prep_q<<<NQ * DH / 8 / 512, 512, 0, stream>>>((const float4*)Q, (ushort8v*)Qb);
  prep_kv<<<NTILES, 256, 0, stream>>>(K, V, Kt, Vt);
  attn_kernel<<<(NQ / 256) * SLICES, 256, 0, stream>>>(Qb, Kt, Vt, Op, Mp, Lp);
  combine_kernel<<<NQ * 16 / 256, 256, 0, stream>>>(Op, Mp, Lp, (float*)d_out);
}

// Round 4
// 118.861 us; speedup vs baseline: 1.0680x; 1.0680x over previous
//
#include <hip/hip_runtime.h>
#include <hip/hip_bf16.h>

#define NQ 8192
#define NK 8192
#define DH 128
#define KVBLK 32
#define SLICES 16
#define KVPER (NK / SLICES)          // 512 kv per slice
#define TILES (KVPER / KVBLK)        // 16 tiles per sweep
#define NTILES (NK / KVBLK)          // 256 global tiles

typedef __attribute__((ext_vector_type(8))) short short8;
typedef __attribute__((ext_vector_type(8))) unsigned short ushort8v;
typedef __attribute__((ext_vector_type(16))) float f32x16;

static __device__ __forceinline__ unsigned short f2bf(float x){
  unsigned u = __builtin_bit_cast(unsigned, x);
  u += 0x7FFFu + ((u >> 16) & 1u);
  return (unsigned short)(u >> 16);
}
static __device__ __forceinline__ float bf2f(unsigned short x){
  unsigned u = ((unsigned)x) << 16;
  return __builtin_bit_cast(float, u);
}
static __device__ __forceinline__ float ex2(float x){
  return __builtin_amdgcn_exp2f(x);            // raw v_exp_f32
}
static __device__ __forceinline__ unsigned cvtpk(float lo, float hi){
  unsigned r;
  asm("v_cvt_pk_bf16_f32 %0, %1, %2" : "=v"(r) : "v"(lo), "v"(hi));
  return r;
}
static __device__ __forceinline__ void gload_lds16(const void* g, void* l){
  __builtin_amdgcn_global_load_lds((const __attribute__((address_space(1))) void*)g,
                                   (__attribute__((address_space(3))) void*)l,
                                   16, 0, 0);
}
// max of 16 floats, max3-fusable tree
static __device__ __forceinline__ float max16(const f32x16& S){
  float t0 = fmaxf(fmaxf(S[0], S[1]), S[2]);
  float t1 = fmaxf(fmaxf(S[3], S[4]), S[5]);
  float t2 = fmaxf(fmaxf(S[6], S[7]), S[8]);
  float t3 = fmaxf(fmaxf(S[9], S[10]), S[11]);
  float t4 = fmaxf(fmaxf(S[12], S[13]), S[14]);
  float u0 = fmaxf(fmaxf(t0, t1), t2);
  float u1 = fmaxf(fmaxf(t3, t4), S[15]);
  return fmaxf(u0, u1);
}
static __device__ __forceinline__ float sum16(const f32x16& S){
  float a0 = (S[0] + S[1]) + (S[2] + S[3]);
  float a1 = (S[4] + S[5]) + (S[6] + S[7]);
  float a2 = (S[8] + S[9]) + (S[10] + S[11]);
  float a3 = (S[12] + S[13]) + (S[14] + S[15]);
  return (a0 + a1) + (a2 + a3);
}

// ---- prep: Q fp32 -> bf16, scaled by log2(e)/sqrt(128) (log2-domain softmax) --
__global__ __launch_bounds__(512) void prep_q(const float4* __restrict__ Q4,
                                              ushort8v* __restrict__ Qb8)
{
  int i = blockIdx.x * 512 + threadIdx.x;
  const float s = 1.4426950408889634f * 0.08838834764831844f;
  float4 a = Q4[2 * i], b = Q4[2 * i + 1];
  ushort8v o;
  o[0]=f2bf(a.x*s); o[1]=f2bf(a.y*s); o[2]=f2bf(a.z*s); o[3]=f2bf(a.w*s);
  o[4]=f2bf(b.x*s); o[5]=f2bf(b.y*s); o[6]=f2bf(b.z*s); o[7]=f2bf(b.w*s);
  Qb8[i] = o;
}

// ---- prep: K,V fp32 -> tiled/permuted/XOR-swizzled bf16 images (8KB tiles) ---
__global__ __launch_bounds__(256) void prep_kv(const float* __restrict__ K,
                                               const float* __restrict__ V,
                                               unsigned char* __restrict__ Kt,
                                               unsigned char* __restrict__ Vt)
{
  __shared__ float vs[KVBLK * DH];             // 16 KiB
  const int tile = blockIdx.x;                 // 256 tiles
  const int tid  = threadIdx.x;

  const float4* Vg = (const float4*)(V + (size_t)tile * KVBLK * DH);
  float4* vs4 = (float4*)vs;
#pragma unroll
  for (int k = 0; k < 4; ++k) vs4[tid + k * 256] = Vg[tid + k * 256];

  unsigned char* Ktb = Kt + (size_t)tile * 8192;
  const float* Kg = K + (size_t)tile * KVBLK * DH;
#pragma unroll
  for (int k2 = 0; k2 < 2; ++k2){
    int task = tid + k2 * 256;                 // 512 tasks: (kv, d0)
    int kv = task >> 4, d0 = (task & 15) * 8;
    const float4* p = (const float4*)(Kg + kv * DH + d0);
    float4 a = p[0], b = p[1];
    ushort8v o;
    o[0]=f2bf(a.x); o[1]=f2bf(a.y); o[2]=f2bf(a.z); o[3]=f2bf(a.w);
    o[4]=f2bf(b.x); o[5]=f2bf(b.y); o[6]=f2bf(b.z); o[7]=f2bf(b.w);
    int addr = (kv * 256 + d0 * 2) ^ ((kv & 7) << 4);
    *(ushort8v*)(Ktb + addr) = o;
  }
  __syncthreads();

  unsigned char* Vtb = Vt + (size_t)tile * 8192;
#pragma unroll
  for (int k2 = 0; k2 < 2; ++k2){
    int task = tid + k2 * 256;                 // 512 tasks: (d, mm, h)
    int d = task >> 2, mm = (task >> 1) & 1, hh = task & 1;
    int kvb = mm * 16 + hh * 4;
    ushort8v o;
    o[0]=f2bf(vs[(kvb+0)*DH + d]);  o[1]=f2bf(vs[(kvb+1)*DH + d]);
    o[2]=f2bf(vs[(kvb+2)*DH + d]);  o[3]=f2bf(vs[(kvb+3)*DH + d]);
    o[4]=f2bf(vs[(kvb+8)*DH + d]);  o[5]=f2bf(vs[(kvb+9)*DH + d]);
    o[6]=f2bf(vs[(kvb+10)*DH + d]); o[7]=f2bf(vs[(kvb+11)*DH + d]);
    int addr = d * 64 + ((mm * 32 + hh * 16) ^ ((d & 3) << 4));
    *(ushort8v*)(Vtb + addr) = o;
  }
}

// ---- main: 4 waves x 64 q-rows, Q-reuse, dbuf LDS, lean softmax --------------
__global__ __launch_bounds__(256, 2) void attn_kernel(
    const unsigned short* __restrict__ Qb,
    const unsigned char* __restrict__ Kt,
    const unsigned char* __restrict__ Vt,
    unsigned short* __restrict__ Opart,   // [SLICES][NQ][DH] bf16
    float* __restrict__ Mpart, float* __restrict__ Lpart)
{
  __shared__ unsigned char lK[2][8192];
  __shared__ unsigned char lV[2][8192];

  const int tid  = threadIdx.x;
  const int lane = tid & 63;
  const int l32  = lane & 31;
  const int h    = lane >> 5;
  const int bq    = blockIdx.x >> 4;       // 0..31
  const int slice = blockIdx.x & 15;       // slice%8 tracks XCD (L2 locality)
  const int qrow0 = bq * 256 + (tid >> 6) * 64;
  const int tile0 = slice * TILES;
  const int kx = (l32 & 7) << 4;
  const int vx = (l32 & 3) << 4;

  const unsigned char* gkb = Kt + (size_t)tile0 * 8192;
  const unsigned char* gvb = Vt + (size_t)tile0 * 8192;

  // Q fragments for two 32-row blocks
  short8 qfA[8], qfB[8];
  {
    const unsigned short* qa = Qb + (size_t)(qrow0 + l32) * DH + 8 * h;
    const unsigned short* qb = qa + 32 * DH;
#pragma unroll
    for (int m = 0; m < 8; ++m){
      qfA[m] = *(const short8*)(qa + 16 * m);
      qfB[m] = *(const short8*)(qb + 16 * m);
    }
  }

  f32x16 accA[4], accB[4];
#pragma unroll
  for (int c = 0; c < 4; ++c)
#pragma unroll
    for (int r = 0; r < 16; ++r){ accA[c][r] = 0.0f; accB[c][r] = 0.0f; }
  float mA = -3.0e38f, lA = 0.0f, mB = -3.0e38f, lB = 0.0f;

  const int soff = tid * 16;
  auto stage = [&](int buf, int t){
    const unsigned char* gk = gkb + (size_t)t * 8192;
    const unsigned char* gv = gvb + (size_t)t * 8192;
    gload_lds16(gk + soff,        &lK[buf][soff]);
    gload_lds16(gk + soff + 4096, &lK[buf][soff + 4096]);
    gload_lds16(gv + soff,        &lV[buf][soff]);
    gload_lds16(gv + soff + 4096, &lV[buf][soff + 4096]);
  };

  stage(0, 0);
  __syncthreads();
  int cur = 0;

  for (int t = 0; t < TILES; ++t){
    if (t + 1 < TILES) stage(cur ^ 1, t + 1);

    const unsigned char* Kb = lK[cur];
    const unsigned char* Vb = lV[cur];

    // ---- S^T = K * Q^T : each K-fragment feeds both q-blocks
    f32x16 SA, SB;
#pragma unroll
    for (int r = 0; r < 16; ++r){ SA[r] = 0.0f; SB[r] = 0.0f; }
    __builtin_amdgcn_s_setprio(1);
#pragma unroll
    for (int m = 0; m < 8; ++m){
      short8 kf = *(const short8*)(Kb + l32 * 256 + ((32 * m + 16 * h) ^ kx));
      SA = __builtin_amdgcn_mfma_f32_32x32x16_bf16(kf, qfA[m], SA, 0, 0, 0);
      SB = __builtin_amdgcn_mfma_f32_32x32x16_bf16(kf, qfB[m], SB, 0, 0, 0);
    }
    __builtin_amdgcn_s_setprio(0);

    // ---- online softmax (log2 domain), lean: max3 tree + raw v_exp
    float pmA = max16(SA), pmB = max16(SB);
    pmA = fmaxf(pmA, __shfl_xor(pmA, 32, 64));
    pmB = fmaxf(pmB, __shfl_xor(pmB, 32, 64));

    if (!__all(pmA <= mA + 8.0f)){
      float mnew = fmaxf(mA, pmA);
      float rs = ex2(mA - mnew);
      lA *= rs; mA = mnew;
#pragma unroll
      for (int r = 0; r < 16; ++r){
        float f = __shfl(rs, (r & 3) + 8 * (r >> 2) + 4 * h, 64);
#pragma unroll
        for (int c = 0; c < 4; ++c) accA[c][r] *= f;
      }
    }
    if (!__all(pmB <= mB + 8.0f)){
      float mnew = fmaxf(mB, pmB);
      float rs = ex2(mB - mnew);
      lB *= rs; mB = mnew;
#pragma unroll
      for (int r = 0; r < 16; ++r){
        float f = __shfl(rs, (r & 3) + 8 * (r >> 2) + 4 * h, 64);
#pragma unroll
        for (int c = 0; c < 4; ++c) accB[c][r] *= f;
      }
    }

#pragma unroll
    for (int r = 0; r < 16; ++r){
      SA[r] = ex2(SA[r] - mA);
      SB[r] = ex2(SB[r] - mB);
    }
    lA += sum16(SA);          // own-half partial; cross-half shfl deferred to end
    lB += sum16(SB);

    // pack P to bf16 via v_cvt_pk (T12)
    union { unsigned u[4]; short8 v; } a0, a1, b0, b1;
#pragma unroll
    for (int e = 0; e < 4; ++e){
      a0.u[e] = cvtpk(SA[2*e],     SA[2*e + 1]);
      a1.u[e] = cvtpk(SA[8 + 2*e], SA[9 + 2*e]);
      b0.u[e] = cvtpk(SB[2*e],     SB[2*e + 1]);
      b1.u[e] = cvtpk(SB[8 + 2*e], SB[9 + 2*e]);
    }

    // ---- PV: each V-fragment feeds both q-blocks
    __builtin_amdgcn_s_setprio(1);
#pragma unroll
    for (int c = 0; c < 4; ++c){
      const unsigned char* vrow = Vb + (32 * c + l32) * 64;
      short8 v0 = *(const short8*)(vrow + ((16 * h) ^ vx));
      short8 v1 = *(const short8*)(vrow + ((32 + 16 * h) ^ vx));
      accA[c] = __builtin_amdgcn_mfma_f32_32x32x16_bf16(a0.v, v0, accA[c], 0, 0, 0);
      accB[c] = __builtin_amdgcn_mfma_f32_32x32x16_bf16(b0.v, v0, accB[c], 0, 0, 0);
      accA[c] = __builtin_amdgcn_mfma_f32_32x32x16_bf16(a1.v, v1, accA[c], 0, 0, 0);
      accB[c] = __builtin_amdgcn_mfma_f32_32x32x16_bf16(b1.v, v1, accB[c], 0, 0, 0);
    }
    __builtin_amdgcn_s_setprio(0);

    __syncthreads();
    cur ^= 1;
  }

  // finish deferred cross-half l reduction
  lA += __shfl_xor(lA, 32, 64);
  lB += __shfl_xor(lB, 32, 64);

  // ---- partials out (bf16 O, fp32 m/l, all log2-domain)
  if (h == 0){
    Mpart[slice * NQ + qrow0 + l32] = mA;
    Lpart[slice * NQ + qrow0 + l32] = lA;
    Mpart[slice * NQ + qrow0 + 32 + l32] = mB;
    Lpart[slice * NQ + qrow0 + 32 + l32] = lB;
  }
  const size_t obase = ((size_t)slice * NQ + qrow0) * DH;
#pragma unroll
  for (int c = 0; c < 4; ++c)
#pragma unroll
    for (int r = 0; r < 16; ++r){
      int q = (r & 3) + 8 * (r >> 2) + 4 * h;
      Opart[obase + (size_t)q * DH + 32 * c + l32]        = f2bf(accA[c][r]);
      Opart[obase + (size_t)(32 + q) * DH + 32 * c + l32] = f2bf(accB[c][r]);
    }
}

// ---- combine 16 kv-slice partials ------------------------------------------
__global__ __launch_bounds__(256) void combine_kernel(
    const unsigned short* __restrict__ Op, const float* __restrict__ Mp,
    const float* __restrict__ Lp, float* __restrict__ Out)
{
  const int idx = blockIdx.x * 256 + threadIdx.x;
  const int q  = idx >> 4;
  const int d8 = (idx & 15) * 8;

  float ms[SLICES], M = -3.0e38f;
#pragma unroll
  for (int s = 0; s < SLICES; ++s){ ms[s] = Mp[s * NQ + q]; M = fmaxf(M, ms[s]); }
  float w[SLICES], L = 0.0f;
#pragma unroll
  for (int s = 0; s < SLICES; ++s){
    w[s] = ex2(ms[s] - M);
    L += Lp[s * NQ + q] * w[s];
  }
  float o[8] = {0,0,0,0,0,0,0,0};
#pragma unroll
  for (int s = 0; s < SLICES; ++s){
    ushort8v v = *(const ushort8v*)(Op + ((size_t)s * NQ + q) * DH + d8);
    float ww = w[s];
#pragma unroll
    for (int e = 0; e < 8; ++e) o[e] += ww * bf2f(v[e]);
  }
  float inv = 1.0f / L;
  float4 o0 = make_float4(o[0]*inv, o[1]*inv, o[2]*inv, o[3]*inv);
  float4 o1 = make_float4(o[4]*inv, o[5]*inv, o[6]*inv, o[7]*inv);
  float4* dst = (float4*)(Out + (size_t)q * DH + d8);
  dst[0] = o0; dst[1] = o1;
}

extern "C" void kernel_launch(void* const* d_in, const int* in_sizes, int n_in,
                              void* d_out, int out_size, void* d_ws, size_t ws_size,
                              hipStream_t stream)
{
  const float* Q = (const float*)d_in[0];
  const float* K = (const float*)d_in[1];
  const float* V = (const float*)d_in[2];

  unsigned char* ws = (unsigned char*)d_ws;
  const size_t MB2 = (size_t)NQ * DH * 2;            // 2 MiB
  unsigned short* Qb = (unsigned short*)ws;          // 2 MiB
  unsigned char*  Kt = ws + MB2;                     // 2 MiB
  unsigned char*  Vt = ws + 2 * MB2;                 // 2 MiB
  float* Mp = (float*)(ws + 3 * MB2);                // 512 KiB
  float* Lp = Mp + (size_t)SLICES * NQ;              // 512 KiB
  unsigned short* Op = (unsigned short*)(Lp + (size_t)SLICES * NQ);  // 32 MiB

  prep_q<<<NQ * DH / 8 / 512, 512, 0, stream>>>((const float4*)Q, (ushort8v*)Qb);
  prep_kv<<<NTILES, 256, 0, stream>>>(K, V, Kt, Vt);
  attn_kernel<<<(NQ / 256) * SLICES, 256, 0, stream>>>(Qb, Kt, Vt, Op, Mp, Lp);
  combine_kernel<<<NQ * 16 / 256, 256, 0, stream>>>(Op, Mp, Lp, (float*)d_out);
}